// Round 6
// baseline (320.037 us; speedup 1.0000x reference)
//
#include <hip/hip_runtime.h>
#include <hip/hip_bf16.h>
#include <cstdint>

// ---------------------------------------------------------------------------
// SingleHeadAttentionLayer: B=4, S=2048, D=KD=VD=1024, fp32 in/out.
// Round 6: load-balanced PV via causal-K chunking (<=8 kSteps64 per block,
// 1280 uniform blocks, fp32 atomicAdd accumulation into pre-zeroed out).
//   out = (P/l)*(x*(Wo*Wv)^T + bv*Wo^T) + bo   (round-5 algebra kept)
// Pipeline:
//   memset out; prep (casts, Wv^T, bvo, zero lsum); Wvo = Wo*Wv;
//   q,k,Ut = x@{Wq,Wk,Wvo}^T + bias  (z=3, XCD-swizzled);
//   P = exp(|q k^T|/32) causal + atomic rowsums;
//   out += chunk(P @ U)/l [+ bo on chunk 0]   (1280 balanced blocks)
// ---------------------------------------------------------------------------

#define BM 128
#define BN 128

typedef __attribute__((ext_vector_type(8))) __bf16 bf16x8;
typedef __attribute__((ext_vector_type(4))) __bf16 bf16x4;
typedef __attribute__((ext_vector_type(4))) float floatx4;

struct WPtr3 { const __bf16* w[3]; };
struct BPtr3 { const float* b[3]; };
struct Ptr3 { const float* p[3]; };

__device__ __forceinline__ void async_copy16(const __bf16* g, const __bf16* l) {
  __builtin_amdgcn_global_load_lds(
      (const __attribute__((address_space(1))) unsigned int*)(const void*)g,
      (__attribute__((address_space(3))) unsigned int*)(unsigned)(uintptr_t)(const void*)l,
      16, 0, 0);
}

// 128x128 tile; K consumed 64/iter as two 32-panels (verified lane-linear
// global_load_lds layout, free 2-way bank pattern). Iterates [kBeg, kEnd).
__device__ __forceinline__ void gemm_core(const __bf16* __restrict__ pA,
                                          const __bf16* __restrict__ pB,
                                          int K, int kBeg, int kEnd, int mb,
                                          int nb, floatx4 (&acc)[4][4]) {
  __shared__ __align__(16) __bf16 As0[BM * 32];
  __shared__ __align__(16) __bf16 As1[BM * 32];
  __shared__ __align__(16) __bf16 Bs0[BN * 32];
  __shared__ __align__(16) __bf16 Bs1[BN * 32];

  const int t = threadIdx.x;
  const int lane = t & 63;
  const int wave = t >> 6;
  const int quad = lane >> 4;
  const int l16 = lane & 15;
  const int wm = wave >> 1;
  const int wn = wave & 1;

  const __bf16* gA = pA + (long)(mb * BM + (t >> 2)) * K + ((t & 3) * 8);
  const __bf16* gB = pB + (long)(nb * BN + (t >> 2)) * K + ((t & 3) * 8);
  const long rowHalf = (long)64 * K;
  __bf16* lA0 = &As0[t * 8];
  __bf16* lA1 = &As1[t * 8];
  __bf16* lB0 = &Bs0[t * 8];
  __bf16* lB1 = &Bs1[t * 8];

  for (int kk = kBeg; kk < kEnd; ++kk) {
    const long ko = (long)kk * 64;
    async_copy16(gA + ko, lA0);
    async_copy16(gA + ko + rowHalf, lA0 + 2048);
    async_copy16(gA + ko + 32, lA1);
    async_copy16(gA + ko + 32 + rowHalf, lA1 + 2048);
    async_copy16(gB + ko, lB0);
    async_copy16(gB + ko + rowHalf, lB0 + 2048);
    async_copy16(gB + ko + 32, lB1);
    async_copy16(gB + ko + 32 + rowHalf, lB1 + 2048);
    __syncthreads();

#pragma unroll
    for (int p = 0; p < 2; ++p) {
      const __bf16* As = p ? As1 : As0;
      const __bf16* Bs = p ? Bs1 : Bs0;
      bf16x8 af[4], bfr[4];
#pragma unroll
      for (int i = 0; i < 4; ++i) {
        af[i] = *(const bf16x8*)&As[(wm * 64 + i * 16 + l16) * 32 + quad * 8];
        bfr[i] = *(const bf16x8*)&Bs[(wn * 64 + i * 16 + l16) * 32 + quad * 8];
      }
#pragma unroll
      for (int i = 0; i < 4; ++i)
#pragma unroll
        for (int j = 0; j < 4; ++j)
          acc[i][j] = __builtin_amdgcn_mfma_f32_16x16x32_bf16(af[i], bfr[j],
                                                              acc[i][j], 0, 0, 0);
    }
    __syncthreads();
  }
}

// ---------------- Wvo = Wo @ Wv  (A=Wob [D][VD], B=Wvt [D][VD]) ------------
__global__ void __launch_bounds__(256, 2)
gemm_wvo(const __bf16* __restrict__ Wob, const __bf16* __restrict__ Wvt,
         __bf16* __restrict__ Wvo) {
  const int id = blockIdx.x;  // 64 blocks: 8x8
  const int mb = id >> 3, nb = id & 7;
  floatx4 acc[4][4] = {};
  gemm_core(Wob, Wvt, 1024, 0, 16, mb, nb, acc);

  const int t = threadIdx.x;
  const int lane = t & 63, wave = t >> 6;
  const int rb = (wave >> 1) * 64 + (lane >> 4) * 4;
  const int cb = (wave & 1) * 64 + (lane & 15);
#pragma unroll
  for (int j4 = 0; j4 < 4; ++j4) {
    const int gc = nb * BN + cb + j4 * 16;
#pragma unroll
    for (int i = 0; i < 4; ++i) {
      const int gr = mb * BM + rb + i * 16;
#pragma unroll
      for (int r = 0; r < 4; ++r)
        Wvo[(long)(gr + r) * 1024 + gc] = (__bf16)acc[i][j4][r];
    }
  }
}

// ---------------- fused QKU projection (z = 0:q, 1:k, 2:U-transposed) -------
__global__ void __launch_bounds__(256, 2)
gemm_qku(const __bf16* __restrict__ xb, WPtr3 wgt, BPtr3 bias,
         __bf16* __restrict__ qk, __bf16* __restrict__ Ut,
         int S, int D, int KD, int B) {
  const int id = blockIdx.x;
  const int xcd = id & 7;
  const int j = id >> 3;          // 192 per XCD
  const int mb = xcd * 8 + (j & 7);
  const int rest = j >> 3;        // 24
  const int nb = rest & 7;
  const int z = rest >> 3;

  floatx4 acc[4][4] = {};
  gemm_core(xb, wgt.w[z], D, 0, D / 64, mb, nb, acc);

  const int t = threadIdx.x;
  const int lane = t & 63, wave = t >> 6;
  const int rb = (wave >> 1) * 64 + (lane >> 4) * 4;
  const int cb = (wave & 1) * 64 + (lane & 15);
  const float* bz = bias.b[z];

  if (z < 2) {
    __bf16* C = qk + (long)z * B * S * KD;
#pragma unroll
    for (int j4 = 0; j4 < 4; ++j4) {
      const int gc = nb * BN + cb + j4 * 16;
      const float bv = bz[gc];
#pragma unroll
      for (int i = 0; i < 4; ++i) {
        const int gr = mb * BM + rb + i * 16;
#pragma unroll
        for (int r = 0; r < 4; ++r)
          C[(long)(gr + r) * KD + gc] = (__bf16)(acc[i][j4][r] + bv);
      }
    }
  } else {
    // Ut[b][dout][s] = U[b][s][dout]
    const int bb = (mb * BM) / S;
    const int s0 = mb * BM - bb * S;
#pragma unroll
    for (int j4 = 0; j4 < 4; ++j4) {
      const int gc = nb * BN + cb + j4 * 16;
      const float bv = bz[gc];
#pragma unroll
      for (int i = 0; i < 4; ++i) {
        const int sr = s0 + rb + i * 16;
        bf16x4 o;
#pragma unroll
        for (int r = 0; r < 4; ++r) o[r] = (__bf16)(acc[i][j4][r] + bv);
        *(bf16x4*)&Ut[((long)bb * D + gc) * S + sr] = o;
      }
    }
  }
}

// ---------------- scores: P = exp(|qk^T|/32) causal, + atomic rowsums -------
__global__ void __launch_bounds__(256, 2)
gemm_scores(const __bf16* __restrict__ q, const __bf16* __restrict__ k,
            __bf16* __restrict__ P, float* __restrict__ lsum, int S, int KD) {
  const int id = blockIdx.x;
  const int xcd = id & 7;
  const int j = id >> 3;          // 128 per XCD
  const int nb = j & 15;
  const int comb = j >> 4;        // 8
  const int b = comb >> 1;
  const int mb = (comb & 1) ? (15 - xcd) : xcd;
  if (nb > mb) return;

  floatx4 acc[4][4] = {};
  gemm_core(q + (long)b * S * KD, k + (long)b * S * KD, KD, 0, KD / 64, mb, nb,
            acc);

  const int t = threadIdx.x;
  const int lane = t & 63, wave = t >> 6;
  const int l16 = lane & 15;
  const int rb = (wave >> 1) * 64 + (lane >> 4) * 4;
  const int cb = (wave & 1) * 64 + l16;
  __bf16* C = P + (long)b * S * S;
  float* lrow = lsum + (long)b * S;
  const float sc = 0.03125f;  // 1/sqrt(1024)

#pragma unroll
  for (int i = 0; i < 4; ++i) {
#pragma unroll
    for (int r = 0; r < 4; ++r) {
      const int row = mb * BM + rb + i * 16 + r;
      float psum = 0.f;
#pragma unroll
      for (int j4 = 0; j4 < 4; ++j4) {
        const int col = nb * BN + cb + j4 * 16;
        const float p = (col <= row) ? __expf(fabsf(acc[i][j4][r] * sc)) : 0.f;
        psum += p;
        C[(long)row * S + col] = (__bf16)p;
      }
      psum += __shfl_xor(psum, 1, 64);
      psum += __shfl_xor(psum, 2, 64);
      psum += __shfl_xor(psum, 4, 64);
      psum += __shfl_xor(psum, 8, 64);
      if (l16 == 0) atomicAdd(&lrow[row], psum);
    }
  }
}

// ---------------- final: out += chunk(P @ U)/l (+bo), fp32 atomics ----------
// 1280 blocks. Per XCD x: mb in {x, 15-x}; nch(x)+nch(15-x) == 5 for all x,
// so each XCD gets exactly 4b * 5ci * 8nb = 160 blocks of <=8 kSteps64.
// out must be pre-zeroed (hipMemsetAsync).
__global__ void __launch_bounds__(256, 2)
gemm_pvo(const __bf16* __restrict__ P, const __bf16* __restrict__ Ut,
         const float* __restrict__ lsum, const float* __restrict__ bo,
         float* __restrict__ out, int S, int D) {
  const int id = blockIdx.x;
  const int xcd = id & 7;
  const int j = id >> 3;          // 0..159
  const int b = j / 40;
  const int rem = j - b * 40;
  const int nb = rem & 7;
  const int ci = rem >> 3;        // 0..4
  const int nchx = (2 * xcd + 9) >> 3;  // nch(xcd): ceil(2(xcd+1)/8)
  const int mb = (ci < nchx) ? xcd : (15 - xcd);
  const int ch = (ci < nchx) ? ci : (ci - nchx);
  const int kBeg = ch * 8;
  const int kEnd = min(kBeg + 8, 2 * (mb + 1));

  floatx4 acc[4][4] = {};
  gemm_core(P + (long)b * S * S, Ut + (long)b * D * S, S, kBeg, kEnd, mb, nb,
            acc);

  const int t = threadIdx.x;
  const int lane = t & 63, wave = t >> 6;
  const int rb = (wave >> 1) * 64 + (lane >> 4) * 4;
  const int cb = (wave & 1) * 64 + (lane & 15);
  const float* lrow = lsum + (long)b * S;

#pragma unroll
  for (int i = 0; i < 4; ++i) {
#pragma unroll
    for (int r = 0; r < 4; ++r) {
      const int row = mb * BM + rb + i * 16 + r;
      const float inv = 1.f / lrow[row];
#pragma unroll
      for (int j4 = 0; j4 < 4; ++j4) {
        const int col = nb * BN + cb + j4 * 16;
        const float add = acc[i][j4][r] * inv + (ch == 0 ? bo[col] : 0.f);
        atomicAdd(&out[((long)b * S + row) * D + col], add);
      }
    }
  }
}

// ---------------- prep --------------------------------------------------
// [0,8192): cast x | [8192,11264): cast Wq,Wk,Wo | [11264,11520): Wv^T cast
// [11520,12544): bvo[d] = sum_v bv[v]*Wo[d][v] | 12544: zero lsum
__global__ void prep(const float* __restrict__ x, Ptr3 wp,
                     const float* __restrict__ Wv, const float* __restrict__ bv,
                     __bf16* __restrict__ xb, __bf16* __restrict__ Wb,
                     __bf16* __restrict__ Wvt, float* __restrict__ bvo,
                     float* __restrict__ lsum) {
  __shared__ __bf16 tile[64][66];
  __shared__ float wsum[4];
  const int bid = blockIdx.x;
  const int t = threadIdx.x;
  if (bid < 8192) {
    const long i = ((long)bid * 256 + t) * 4;
    const float4 f = *(const float4*)(x + i);
    bf16x4 o;
    o[0] = (__bf16)f.x; o[1] = (__bf16)f.y; o[2] = (__bf16)f.z; o[3] = (__bf16)f.w;
    *(bf16x4*)(xb + i) = o;
  } else if (bid < 11264) {
    const int slot = (bid - 8192) * 256 + t;
    const int which = slot >> 18;
    const long e = (long)(slot & 0x3ffff) * 4;
    const float4 f = *(const float4*)(wp.p[which] + e);
    bf16x4 o;
    o[0] = (__bf16)f.x; o[1] = (__bf16)f.y; o[2] = (__bf16)f.z; o[3] = (__bf16)f.w;
    *(bf16x4*)(Wb + ((long)which << 20) + e) = o;
  } else if (bid < 11520) {
    const int idx = bid - 11264;
    const int r0 = (idx >> 4) * 64, c0 = (idx & 15) * 64;
#pragma unroll
    for (int e = 0; e < 16; ++e) {
      const int i = e * 256 + t;
      const int r = i >> 6, c = i & 63;
      tile[r][c] = (__bf16)Wv[(long)(r0 + r) * 1024 + (c0 + c)];
    }
    __syncthreads();
#pragma unroll
    for (int e = 0; e < 16; ++e) {
      const int i = e * 256 + t;
      const int r = i >> 6, c = i & 63;
      Wvt[(long)(c0 + r) * 1024 + (r0 + c)] = tile[c][r];
    }
  } else if (bid < 12544) {
    const int d = bid - 11520;
    const float* row = wp.p[2] + (long)d * 1024;
    float s = 0.f;
    for (int v = t; v < 1024; v += 256) s += bv[v] * row[v];
#pragma unroll
    for (int off = 32; off > 0; off >>= 1) s += __shfl_down(s, off, 64);
    if ((t & 63) == 0) wsum[t >> 6] = s;
    __syncthreads();
    if (t == 0) bvo[d] = wsum[0] + wsum[1] + wsum[2] + wsum[3];
  } else {
#pragma unroll
    for (int e = 0; e < 8; ++e)
      *(float4*)(lsum + (e * 256 + t) * 4) = float4{0.f, 0.f, 0.f, 0.f};
  }
}

extern "C" void kernel_launch(void* const* d_in, const int* in_sizes, int n_in,
                              void* d_out, int out_size, void* d_ws, size_t ws_size,
                              hipStream_t stream) {
  const float* x = (const float*)d_in[0];
  const float* Wq = (const float*)d_in[1];
  const float* bq = (const float*)d_in[2];
  const float* Wk = (const float*)d_in[3];
  const float* bk = (const float*)d_in[4];
  const float* Wv = (const float*)d_in[5];
  const float* bv = (const float*)d_in[6];
  const float* Wo = (const float*)d_in[7];
  const float* bo = (const float*)d_in[8];
  float* out = (float*)d_out;

  constexpr int B = 4, S = 2048, D = 1024, KD = 1024;
  constexpr long MB_ = 1024 * 1024;

  char* w = (char*)d_ws;
  __bf16* xb = (__bf16*)(w);               // 16 MB
  __bf16* qk = (__bf16*)(w + 16 * MB_);    // 32 MB: q then k
  __bf16* Ut = (__bf16*)(w + 48 * MB_);    // 16 MB
  __bf16* P  = (__bf16*)(w + 64 * MB_);    // 32 MB
  __bf16* Wb = (__bf16*)(w + 96 * MB_);    // 6 MB: Wqb, Wkb, Wob
  __bf16* Wvt = (__bf16*)(w + 102 * MB_);  // 2 MB
  __bf16* Wvo = (__bf16*)(w + 104 * MB_);  // 2 MB
  float* lsum = (float*)(w + 106 * MB_);   // 32 KB
  float* bvo = (float*)(w + 106 * MB_ + 65536);  // 4 KB

  __bf16* Wqb = Wb;
  __bf16* Wkb = Wb + (1l << 20);
  __bf16* Wob = Wb + (2l << 20);

  // out accumulated via atomics -> zero it (poisoned 0xAA before every call)
  hipMemsetAsync(out, 0, (long)B * S * D * sizeof(float), stream);

  Ptr3 wp{{Wq, Wk, Wo}};
  prep<<<12545, 256, 0, stream>>>(x, wp, Wv, bv, xb, Wb, Wvt, bvo, lsum);

  gemm_wvo<<<64, 256, 0, stream>>>(Wob, Wvt, Wvo);

  WPtr3 w3{{Wqb, Wkb, Wvo}};
  BPtr3 b3{{bq, bk, bvo}};
  gemm_qku<<<1536, 256, 0, stream>>>(xb, w3, b3, qk, Ut, S, D, KD, B);

  gemm_scores<<<1024, 256, 0, stream>>>(qk, qk + (long)B * S * KD, P, lsum, S, KD);

  gemm_pvo<<<1280, 256, 0, stream>>>(P, Ut, lsum, bo, out, S, D);
}

// Round 7
// 266.927 us; speedup vs baseline: 1.1990x; 1.1990x over previous
//
#include <hip/hip_runtime.h>
#include <hip/hip_bf16.h>
#include <cstdint>

// ---------------------------------------------------------------------------
// SingleHeadAttentionLayer: B=4, S=2048, D=KD=VD=1024, fp32 in/out.
// Round 7: revert r6 atomics (epilogue-bound, 84M atomic RMWs). Attention
// pair moves to BN=64 tiles with exactly-packed, XCD-balanced grids:
//   scores: 1088 blocks, all active, uniform 16 kSteps (pair {x,15-x} -> 34
//           tiles per XCD/batch), P bf16 + atomic rowsums.
//   pv:     1024 blocks, plain fp32 stores, pair-balanced kSteps.
// qku/wvo keep the 128x128 core (template JW).
//   out = (P/l)*(x*(Wo*Wv)^T + bv*Wo^T) + bo   (round-5 algebra)
// ---------------------------------------------------------------------------

#define BM 128

typedef __attribute__((ext_vector_type(8))) __bf16 bf16x8;
typedef __attribute__((ext_vector_type(4))) __bf16 bf16x4;
typedef __attribute__((ext_vector_type(4))) float floatx4;

struct WPtr3 { const __bf16* w[3]; };
struct BPtr3 { const float* b[3]; };
struct Ptr3 { const float* p[3]; };

__device__ __forceinline__ void async_copy16(const __bf16* g, const __bf16* l) {
  __builtin_amdgcn_global_load_lds(
      (const __attribute__((address_space(1))) unsigned int*)(const void*)g,
      (__attribute__((address_space(3))) unsigned int*)(unsigned)(uintptr_t)(const void*)l,
      16, 0, 0);
}

// 128 x (JW*32) tile; K consumed 64/iter as two 32-panels (verified
// lane-linear global_load_lds layout, free 2-way bank pattern).
// JW=4: 128-wide (2x2 waves of 64x64); JW=2: 64-wide (2x2 waves of 64x32).
template <int JW>
__device__ __forceinline__ void gemm_core(const __bf16* __restrict__ pA,
                                          const __bf16* __restrict__ pB,
                                          int K, int kBeg, int kEnd, int mb,
                                          int nb, floatx4 (&acc)[4][JW]) {
  constexpr int BN_ = JW * 32;
  __shared__ __align__(16) __bf16 As0[BM * 32];
  __shared__ __align__(16) __bf16 As1[BM * 32];
  __shared__ __align__(16) __bf16 Bs0[BN_ * 32];
  __shared__ __align__(16) __bf16 Bs1[BN_ * 32];

  const int t = threadIdx.x;
  const int lane = t & 63;
  const int wave = t >> 6;
  const int quad = lane >> 4;
  const int l16 = lane & 15;
  const int wm = wave >> 1;
  const int wn = wave & 1;

  const __bf16* gA = pA + (long)(mb * BM + (t >> 2)) * K + ((t & 3) * 8);
  const __bf16* gB = pB + (long)(nb * BN_ + (t >> 2)) * K + ((t & 3) * 8);
  const long rowHalf = (long)64 * K;
  __bf16* lA0 = &As0[t * 8];
  __bf16* lA1 = &As1[t * 8];
  __bf16* lB0 = &Bs0[t * 8];
  __bf16* lB1 = &Bs1[t * 8];

  for (int kk = kBeg; kk < kEnd; ++kk) {
    const long ko = (long)kk * 64;
    async_copy16(gA + ko, lA0);
    async_copy16(gA + ko + rowHalf, lA0 + 2048);
    async_copy16(gA + ko + 32, lA1);
    async_copy16(gA + ko + 32 + rowHalf, lA1 + 2048);
    async_copy16(gB + ko, lB0);
    async_copy16(gB + ko + 32, lB1);
    if (JW == 4) {  // second 64-row half of the B tile
      async_copy16(gB + ko + rowHalf, lB0 + 2048);
      async_copy16(gB + ko + 32 + rowHalf, lB1 + 2048);
    }
    __syncthreads();

#pragma unroll
    for (int p = 0; p < 2; ++p) {
      const __bf16* As = p ? As1 : As0;
      const __bf16* Bs = p ? Bs1 : Bs0;
      bf16x8 af[4], bfr[JW];
#pragma unroll
      for (int i = 0; i < 4; ++i)
        af[i] = *(const bf16x8*)&As[(wm * 64 + i * 16 + l16) * 32 + quad * 8];
#pragma unroll
      for (int j = 0; j < JW; ++j)
        bfr[j] =
            *(const bf16x8*)&Bs[(wn * (JW * 16) + j * 16 + l16) * 32 + quad * 8];
#pragma unroll
      for (int i = 0; i < 4; ++i)
#pragma unroll
        for (int j = 0; j < JW; ++j)
          acc[i][j] = __builtin_amdgcn_mfma_f32_16x16x32_bf16(af[i], bfr[j],
                                                              acc[i][j], 0, 0, 0);
    }
    __syncthreads();
  }
}

// ---------------- Wvo = Wo @ Wv  (A=Wob [D][VD], B=Wvt [D][VD]) ------------
__global__ void __launch_bounds__(256, 2)
gemm_wvo(const __bf16* __restrict__ Wob, const __bf16* __restrict__ Wvt,
         __bf16* __restrict__ Wvo) {
  const int id = blockIdx.x;  // 64 blocks: 8x8
  const int mb = id >> 3, nb = id & 7;
  floatx4 acc[4][4] = {};
  gemm_core<4>(Wob, Wvt, 1024, 0, 16, mb, nb, acc);

  const int t = threadIdx.x;
  const int lane = t & 63, wave = t >> 6;
  const int rb = (wave >> 1) * 64 + (lane >> 4) * 4;
  const int cb = (wave & 1) * 64 + (lane & 15);
#pragma unroll
  for (int j4 = 0; j4 < 4; ++j4) {
    const int gc = nb * 128 + cb + j4 * 16;
#pragma unroll
    for (int i = 0; i < 4; ++i) {
      const int gr = mb * BM + rb + i * 16;
#pragma unroll
      for (int r = 0; r < 4; ++r)
        Wvo[(long)(gr + r) * 1024 + gc] = (__bf16)acc[i][j4][r];
    }
  }
}

// ---------------- fused QKU projection (z = 0:q, 1:k, 2:U-transposed) -------
__global__ void __launch_bounds__(256, 2)
gemm_qku(const __bf16* __restrict__ xb, WPtr3 wgt, BPtr3 bias,
         __bf16* __restrict__ qk, __bf16* __restrict__ Ut,
         int S, int D, int KD, int B) {
  const int id = blockIdx.x;
  const int xcd = id & 7;
  const int j = id >> 3;          // 192 per XCD
  const int mb = xcd * 8 + (j & 7);
  const int rest = j >> 3;        // 24
  const int nb = rest & 7;
  const int z = rest >> 3;

  floatx4 acc[4][4] = {};
  gemm_core<4>(xb, wgt.w[z], D, 0, D / 64, mb, nb, acc);

  const int t = threadIdx.x;
  const int lane = t & 63, wave = t >> 6;
  const int rb = (wave >> 1) * 64 + (lane >> 4) * 4;
  const int cb = (wave & 1) * 64 + (lane & 15);
  const float* bz = bias.b[z];

  if (z < 2) {
    __bf16* C = qk + (long)z * B * S * KD;
#pragma unroll
    for (int j4 = 0; j4 < 4; ++j4) {
      const int gc = nb * 128 + cb + j4 * 16;
      const float bv = bz[gc];
#pragma unroll
      for (int i = 0; i < 4; ++i) {
        const int gr = mb * BM + rb + i * 16;
#pragma unroll
        for (int r = 0; r < 4; ++r)
          C[(long)(gr + r) * KD + gc] = (__bf16)(acc[i][j4][r] + bv);
      }
    }
  } else {
    // Ut[b][dout][s] = U[b][s][dout]
    const int bb = (mb * BM) / S;
    const int s0 = mb * BM - bb * S;
#pragma unroll
    for (int j4 = 0; j4 < 4; ++j4) {
      const int gc = nb * 128 + cb + j4 * 16;
      const float bv = bz[gc];
#pragma unroll
      for (int i = 0; i < 4; ++i) {
        const int sr = s0 + rb + i * 16;
        bf16x4 o;
#pragma unroll
        for (int r = 0; r < 4; ++r) o[r] = (__bf16)(acc[i][j4][r] + bv);
        *(bf16x4*)&Ut[((long)bb * D + gc) * S + sr] = o;
      }
    }
  }
}

// ---------------- scores: P = exp(|qk^T|/32) causal, + atomic rowsums -------
// BN=64 tiles. Per (XCD x, batch): pair {x, 15-x} has (2x+2)+(32-2x) = 34
// active 64-col tiles -> grid 8*4*34 = 1088, ALL blocks active & uniform.
__global__ void __launch_bounds__(256, 2)
gemm_scores(const __bf16* __restrict__ q, const __bf16* __restrict__ k,
            __bf16* __restrict__ P, float* __restrict__ lsum, int S, int KD) {
  const int id = blockIdx.x;
  const int xcd = id & 7;
  const int j = id >> 3;          // 136 per XCD
  const int b = j / 34;
  const int ci = j - b * 34;      // 0..33
  const int n1 = 2 * xcd + 2;     // tiles for mb = xcd
  const int mb = (ci < n1) ? xcd : (15 - xcd);
  const int nb = (ci < n1) ? ci : (ci - n1);

  floatx4 acc[4][2] = {};
  gemm_core<2>(q + (long)b * S * KD, k + (long)b * S * KD, KD, 0, KD / 64, mb,
               nb, acc);

  const int t = threadIdx.x;
  const int lane = t & 63, wave = t >> 6;
  const int l16 = lane & 15;
  const int rb = (wave >> 1) * 64 + (lane >> 4) * 4;
  const int cb = (wave & 1) * 32 + l16;
  __bf16* C = P + (long)b * S * S;
  float* lrow = lsum + (long)b * S;
  const float sc = 0.03125f;  // 1/sqrt(1024)

#pragma unroll
  for (int i = 0; i < 4; ++i) {
#pragma unroll
    for (int r = 0; r < 4; ++r) {
      const int row = mb * BM + rb + i * 16 + r;
      float psum = 0.f;
#pragma unroll
      for (int j4 = 0; j4 < 2; ++j4) {
        const int col = nb * 64 + cb + j4 * 16;
        const float p = (col <= row) ? __expf(fabsf(acc[i][j4][r] * sc)) : 0.f;
        psum += p;
        C[(long)row * S + col] = (__bf16)p;
      }
      psum += __shfl_xor(psum, 1, 64);
      psum += __shfl_xor(psum, 2, 64);
      psum += __shfl_xor(psum, 4, 64);
      psum += __shfl_xor(psum, 8, 64);
      if (l16 == 0) atomicAdd(&lrow[row], psum);
    }
  }
}

// ---------------- final: out = (P @ U)/l + bo, fp32, plain stores -----------
// BN=64 tiles of D: 16 mb x 16 nb x 4 b = 1024 blocks; pair {x,15-x} per XCD
// balances kSteps (34 per pair-slot). Each output element written once.
__global__ void __launch_bounds__(256, 2)
gemm_pvo(const __bf16* __restrict__ P, const __bf16* __restrict__ Ut,
         const float* __restrict__ lsum, const float* __restrict__ bo,
         float* __restrict__ out, int S, int D) {
  const int id = blockIdx.x;
  const int xcd = id & 7;
  const int j = id >> 3;          // 128 per XCD
  const int b = j >> 5;
  const int rem = j & 31;
  const int nb = rem & 15;
  const int mb = (rem >> 4) ? (15 - xcd) : xcd;

  floatx4 acc[4][2] = {};
  gemm_core<2>(P + (long)b * S * S, Ut + (long)b * D * S, S, 0, 2 * (mb + 1),
               mb, nb, acc);

  const int t = threadIdx.x;
  const int lane = t & 63, wave = t >> 6;
  const int rb = (wave >> 1) * 64 + (lane >> 4) * 4;
  const int cb = (wave & 1) * 32 + (lane & 15);
  const float* lrow = lsum + (long)b * S;

#pragma unroll
  for (int i = 0; i < 4; ++i) {
#pragma unroll
    for (int r = 0; r < 4; ++r) {
      const int row = mb * BM + rb + i * 16 + r;
      const float inv = 1.f / lrow[row];
#pragma unroll
      for (int j4 = 0; j4 < 2; ++j4) {
        const int col = nb * 64 + cb + j4 * 16;
        out[((long)b * S + row) * D + col] = acc[i][j4][r] * inv + bo[col];
      }
    }
  }
}

// ---------------- prep --------------------------------------------------
// [0,8192): cast x | [8192,11264): cast Wq,Wk,Wo | [11264,11520): Wv^T cast
// [11520,12544): bvo[d] = sum_v bv[v]*Wo[d][v] | 12544: zero lsum
__global__ void prep(const float* __restrict__ x, Ptr3 wp,
                     const float* __restrict__ Wv, const float* __restrict__ bv,
                     __bf16* __restrict__ xb, __bf16* __restrict__ Wb,
                     __bf16* __restrict__ Wvt, float* __restrict__ bvo,
                     float* __restrict__ lsum) {
  __shared__ __bf16 tile[64][66];
  __shared__ float wsum[4];
  const int bid = blockIdx.x;
  const int t = threadIdx.x;
  if (bid < 8192) {
    const long i = ((long)bid * 256 + t) * 4;
    const float4 f = *(const float4*)(x + i);
    bf16x4 o;
    o[0] = (__bf16)f.x; o[1] = (__bf16)f.y; o[2] = (__bf16)f.z; o[3] = (__bf16)f.w;
    *(bf16x4*)(xb + i) = o;
  } else if (bid < 11264) {
    const int slot = (bid - 8192) * 256 + t;
    const int which = slot >> 18;
    const long e = (long)(slot & 0x3ffff) * 4;
    const float4 f = *(const float4*)(wp.p[which] + e);
    bf16x4 o;
    o[0] = (__bf16)f.x; o[1] = (__bf16)f.y; o[2] = (__bf16)f.z; o[3] = (__bf16)f.w;
    *(bf16x4*)(Wb + ((long)which << 20) + e) = o;
  } else if (bid < 11520) {
    const int idx = bid - 11264;
    const int r0 = (idx >> 4) * 64, c0 = (idx & 15) * 64;
#pragma unroll
    for (int e = 0; e < 16; ++e) {
      const int i = e * 256 + t;
      const int r = i >> 6, c = i & 63;
      tile[r][c] = (__bf16)Wv[(long)(r0 + r) * 1024 + (c0 + c)];
    }
    __syncthreads();
#pragma unroll
    for (int e = 0; e < 16; ++e) {
      const int i = e * 256 + t;
      const int r = i >> 6, c = i & 63;
      Wvt[(long)(c0 + r) * 1024 + (r0 + c)] = tile[c][r];
    }
  } else if (bid < 12544) {
    const int d = bid - 11520;
    const float* row = wp.p[2] + (long)d * 1024;
    float s = 0.f;
    for (int v = t; v < 1024; v += 256) s += bv[v] * row[v];
#pragma unroll
    for (int off = 32; off > 0; off >>= 1) s += __shfl_down(s, off, 64);
    if ((t & 63) == 0) wsum[t >> 6] = s;
    __syncthreads();
    if (t == 0) bvo[d] = wsum[0] + wsum[1] + wsum[2] + wsum[3];
  } else {
#pragma unroll
    for (int e = 0; e < 8; ++e)
      *(float4*)(lsum + (e * 256 + t) * 4) = float4{0.f, 0.f, 0.f, 0.f};
  }
}

extern "C" void kernel_launch(void* const* d_in, const int* in_sizes, int n_in,
                              void* d_out, int out_size, void* d_ws, size_t ws_size,
                              hipStream_t stream) {
  const float* x = (const float*)d_in[0];
  const float* Wq = (const float*)d_in[1];
  const float* bq = (const float*)d_in[2];
  const float* Wk = (const float*)d_in[3];
  const float* bk = (const float*)d_in[4];
  const float* Wv = (const float*)d_in[5];
  const float* bv = (const float*)d_in[6];
  const float* Wo = (const float*)d_in[7];
  const float* bo = (const float*)d_in[8];
  float* out = (float*)d_out;

  constexpr int B = 4, S = 2048, D = 1024, KD = 1024;
  constexpr long MB_ = 1024 * 1024;

  char* w = (char*)d_ws;
  __bf16* xb = (__bf16*)(w);               // 16 MB
  __bf16* qk = (__bf16*)(w + 16 * MB_);    // 32 MB: q then k
  __bf16* Ut = (__bf16*)(w + 48 * MB_);    // 16 MB
  __bf16* P  = (__bf16*)(w + 64 * MB_);    // 32 MB
  __bf16* Wb = (__bf16*)(w + 96 * MB_);    // 6 MB: Wqb, Wkb, Wob
  __bf16* Wvt = (__bf16*)(w + 102 * MB_);  // 2 MB
  __bf16* Wvo = (__bf16*)(w + 104 * MB_);  // 2 MB
  float* lsum = (float*)(w + 106 * MB_);   // 32 KB
  float* bvo = (float*)(w + 106 * MB_ + 65536);  // 4 KB

  __bf16* Wqb = Wb;
  __bf16* Wkb = Wb + (1l << 20);
  __bf16* Wob = Wb + (2l << 20);

  Ptr3 wp{{Wq, Wk, Wo}};
  prep<<<12545, 256, 0, stream>>>(x, wp, Wv, bv, xb, Wb, Wvt, bvo, lsum);

  gemm_wvo<<<64, 256, 0, stream>>>(Wob, Wvt, Wvo);

  WPtr3 w3{{Wqb, Wkb, Wvo}};
  BPtr3 b3{{bq, bk, bvo}};
  gemm_qku<<<1536, 256, 0, stream>>>(xb, w3, b3, qk, Ut, S, D, KD, B);

  gemm_scores<<<1088, 256, 0, stream>>>(qk, qk + (long)B * S * KD, P, lsum, S, KD);

  gemm_pvo<<<1024, 256, 0, stream>>>(P, Ut, lsum, bo, out, S, D);
}

// Round 8
// 248.565 us; speedup vs baseline: 1.2875x; 1.0739x over previous
//
#include <hip/hip_runtime.h>
#include <hip/hip_bf16.h>
#include <cstdint>

// ---------------------------------------------------------------------------
// SingleHeadAttentionLayer: B=4, S=2048, D=KD=VD=1024, fp32 in/out.
// Round 8: all-128x128 tiles; co-residency fixed by merging independent
// workloads into shared dispatches (not by shrinking tiles, which round 7
// showed costs ~2x per-kStep efficiency):
//   prep:      casts, Wv^T, bvo, zero lsum
//   fusedA:    q,k = x@{Wq,Wk}^T + b   (1024 blk)  +  Wvo = Wo@Wv (64 blk)
//   fusedB:    Ut = (x@Wvo^T + bvo)^T  (512 blk)   +  P = exp(|qk^T|/32)
//              causal + atomic rowsums (544 blk, exact-packed pairs {x,15-x})
//   pvo:       out = (P@U)/l + bo      (512 blk, heavy-first pair balance)
//   out = (P/l)*(x*(Wo*Wv)^T + bv*Wo^T) + bo   (round-5 algebra)
// ---------------------------------------------------------------------------

#define BM 128

typedef __attribute__((ext_vector_type(8))) __bf16 bf16x8;
typedef __attribute__((ext_vector_type(4))) __bf16 bf16x4;
typedef __attribute__((ext_vector_type(4))) float floatx4;

struct Ptr3 { const float* p[3]; };

__device__ __forceinline__ void async_copy16(const __bf16* g, const __bf16* l) {
  __builtin_amdgcn_global_load_lds(
      (const __attribute__((address_space(1))) unsigned int*)(const void*)g,
      (__attribute__((address_space(3))) unsigned int*)(unsigned)(uintptr_t)(const void*)l,
      16, 0, 0);
}

// 128x128 tile; K consumed 64/iter as two 32-panels (verified lane-linear
// global_load_lds layout, free 2-way bank pattern). Iterates [kBeg, kEnd).
// MUST be called from exactly ONE call site per kernel (single 32 KB LDS).
__device__ __forceinline__ void gemm_core(const __bf16* __restrict__ pA,
                                          const __bf16* __restrict__ pB,
                                          int K, int kBeg, int kEnd, int mb,
                                          int nb, floatx4 (&acc)[4][4]) {
  __shared__ __align__(16) __bf16 As0[BM * 32];
  __shared__ __align__(16) __bf16 As1[BM * 32];
  __shared__ __align__(16) __bf16 Bs0[BM * 32];
  __shared__ __align__(16) __bf16 Bs1[BM * 32];

  const int t = threadIdx.x;
  const int lane = t & 63;
  const int wave = t >> 6;
  const int quad = lane >> 4;
  const int l16 = lane & 15;
  const int wm = wave >> 1;
  const int wn = wave & 1;

  const __bf16* gA = pA + (long)(mb * BM + (t >> 2)) * K + ((t & 3) * 8);
  const __bf16* gB = pB + (long)(nb * BM + (t >> 2)) * K + ((t & 3) * 8);
  const long rowHalf = (long)64 * K;
  __bf16* lA0 = &As0[t * 8];
  __bf16* lA1 = &As1[t * 8];
  __bf16* lB0 = &Bs0[t * 8];
  __bf16* lB1 = &Bs1[t * 8];

  for (int kk = kBeg; kk < kEnd; ++kk) {
    const long ko = (long)kk * 64;
    async_copy16(gA + ko, lA0);
    async_copy16(gA + ko + rowHalf, lA0 + 2048);
    async_copy16(gA + ko + 32, lA1);
    async_copy16(gA + ko + 32 + rowHalf, lA1 + 2048);
    async_copy16(gB + ko, lB0);
    async_copy16(gB + ko + rowHalf, lB0 + 2048);
    async_copy16(gB + ko + 32, lB1);
    async_copy16(gB + ko + 32 + rowHalf, lB1 + 2048);
    __syncthreads();

#pragma unroll
    for (int p = 0; p < 2; ++p) {
      const __bf16* As = p ? As1 : As0;
      const __bf16* Bs = p ? Bs1 : Bs0;
      bf16x8 af[4], bfr[4];
#pragma unroll
      for (int i = 0; i < 4; ++i) {
        af[i] = *(const bf16x8*)&As[(wm * 64 + i * 16 + l16) * 32 + quad * 8];
        bfr[i] = *(const bf16x8*)&Bs[(wn * 64 + i * 16 + l16) * 32 + quad * 8];
      }
#pragma unroll
      for (int i = 0; i < 4; ++i)
#pragma unroll
        for (int j = 0; j < 4; ++j)
          acc[i][j] = __builtin_amdgcn_mfma_f32_16x16x32_bf16(af[i], bfr[j],
                                                              acc[i][j], 0, 0, 0);
    }
    __syncthreads();
  }
}

// ---------------- dispatch A: qk projections (1024) + Wvo GEMM (64) ---------
__global__ void __launch_bounds__(256, 2)
fusedA(const __bf16* __restrict__ xb, const __bf16* __restrict__ Wb,
       const float* __restrict__ bq, const float* __restrict__ bk,
       __bf16* __restrict__ qk, const __bf16* __restrict__ Wob,
       const __bf16* __restrict__ Wvt, __bf16* __restrict__ Wvo,
       int S, int KD, int B) {
  const int id = blockIdx.x;
  const __bf16 *pA, *pB;
  int mb, nb, z;
  if (id < 1024) {  // q,k projections, XCD-swizzled (r4-verified)
    const int xcd = id & 7;
    const int j = id >> 3;        // 128 per XCD
    mb = xcd * 8 + (j & 7);
    const int rest = j >> 3;      // 16
    nb = rest & 7;
    z = rest >> 3;                // 0:q 1:k
    pA = xb;
    pB = Wb + ((long)z << 20);
  } else {  // Wvo = Wo @ Wv
    const int wid = id - 1024;
    mb = wid >> 3;
    nb = wid & 7;
    z = 2;
    pA = Wob;
    pB = Wvt;
  }

  floatx4 acc[4][4] = {};
  gemm_core(pA, pB, KD, 0, KD / 64, mb, nb, acc);

  const int t = threadIdx.x;
  const int lane = t & 63, wave = t >> 6;
  const int rb = (wave >> 1) * 64 + (lane >> 4) * 4;
  const int cb = (wave & 1) * 64 + (lane & 15);

  if (z < 2) {
    __bf16* C = qk + (long)z * B * S * KD;
    const float* bz = z ? bk : bq;
#pragma unroll
    for (int j4 = 0; j4 < 4; ++j4) {
      const int gc = nb * 128 + cb + j4 * 16;
      const float bv = bz[gc];
#pragma unroll
      for (int i = 0; i < 4; ++i) {
        const int gr = mb * BM + rb + i * 16;
#pragma unroll
        for (int r = 0; r < 4; ++r)
          C[(long)(gr + r) * KD + gc] = (__bf16)(acc[i][j4][r] + bv);
      }
    }
  } else {
#pragma unroll
    for (int j4 = 0; j4 < 4; ++j4) {
      const int gc = nb * 128 + cb + j4 * 16;
#pragma unroll
      for (int i = 0; i < 4; ++i) {
        const int gr = mb * BM + rb + i * 16;
#pragma unroll
        for (int r = 0; r < 4; ++r)
          Wvo[(long)(gr + r) * 1024 + gc] = (__bf16)acc[i][j4][r];
      }
    }
  }
}

// ---------------- dispatch B: U projection (512) + scores (544) -------------
__global__ void __launch_bounds__(256, 2)
fusedB(const __bf16* __restrict__ xb, const __bf16* __restrict__ Wvo,
       const float* __restrict__ bvo, __bf16* __restrict__ Ut,
       const __bf16* __restrict__ q, const __bf16* __restrict__ k,
       __bf16* __restrict__ P, float* __restrict__ lsum,
       int S, int KD, int D) {
  const int id = blockIdx.x;
  const __bf16 *pA, *pB;
  int mb, nb, b, mode;
  if (id < 512) {  // Ut = (x @ Wvo^T + bvo)^T
    const int xcd = id & 7;
    const int j = id >> 3;        // 64 per XCD
    mb = xcd * 8 + (j & 7);
    nb = j >> 3;
    b = 0;
    mode = 0;
    pA = xb;
    pB = Wvo;
  } else {  // scores, exact-packed: 17 uniform tiles per (XCD, batch)
    const int sid = id - 512;
    const int xcd = sid & 7;
    const int r = sid >> 3;       // 0..67
    b = r / 17;
    const int ci = r - b * 17;    // 0..16
    const int n1 = xcd + 1;       // tiles for mb = xcd
    mb = (ci < n1) ? xcd : (15 - xcd);
    nb = (ci < n1) ? ci : (ci - n1);
    mode = 1;
    pA = q + (long)b * S * KD;
    pB = k + (long)b * S * KD;
  }

  floatx4 acc[4][4] = {};
  gemm_core(pA, pB, KD, 0, KD / 64, mb, nb, acc);

  const int t = threadIdx.x;
  const int lane = t & 63, wave = t >> 6;
  const int l16 = lane & 15;
  const int rb = (wave >> 1) * 64 + (lane >> 4) * 4;
  const int cb = (wave & 1) * 64 + l16;

  if (mode == 0) {
    // Ut[bb][dout][s] = U[bb][s][dout]; BM=128 rows lie in one batch
    const int bb = (mb * BM) / S;
    const int s0 = mb * BM - bb * S;
#pragma unroll
    for (int j4 = 0; j4 < 4; ++j4) {
      const int gc = nb * 128 + cb + j4 * 16;
      const float bv = bvo[gc];
#pragma unroll
      for (int i = 0; i < 4; ++i) {
        const int sr = s0 + rb + i * 16;
        bf16x4 o;
#pragma unroll
        for (int r = 0; r < 4; ++r) o[r] = (__bf16)(acc[i][j4][r] + bv);
        *(bf16x4*)&Ut[((long)bb * D + gc) * S + sr] = o;
      }
    }
  } else {
    __bf16* C = P + (long)b * S * S;
    float* lrow = lsum + (long)b * S;
    const float sc = 0.03125f;  // 1/sqrt(1024)
#pragma unroll
    for (int i = 0; i < 4; ++i) {
#pragma unroll
      for (int r = 0; r < 4; ++r) {
        const int row = mb * BM + rb + i * 16 + r;
        float psum = 0.f;
#pragma unroll
        for (int j4 = 0; j4 < 4; ++j4) {
          const int col = nb * 128 + cb + j4 * 16;
          const float p = (col <= row) ? __expf(fabsf(acc[i][j4][r] * sc)) : 0.f;
          psum += p;
          C[(long)row * S + col] = (__bf16)p;
        }
        // 16 lanes of this quad share `row`: butterfly then one atomic
        psum += __shfl_xor(psum, 1, 64);
        psum += __shfl_xor(psum, 2, 64);
        psum += __shfl_xor(psum, 4, 64);
        psum += __shfl_xor(psum, 8, 64);
        if (l16 == 0) atomicAdd(&lrow[row], psum);
      }
    }
  }
}

// ---------------- dispatch C: out = (P @ U)/l + bo, fp32 --------------------
// 512 blocks; per XCD x: first 32 blocks mb=15-x (heavy, 32-2x kSteps), next
// 32 mb=x (light, 2x+2) -> round-robin CU fill pairs heavy+light = 34/CU.
__global__ void __launch_bounds__(256, 2)
gemm_pvo(const __bf16* __restrict__ P, const __bf16* __restrict__ Ut,
         const float* __restrict__ lsum, const float* __restrict__ bo,
         float* __restrict__ out, int S, int D) {
  const int id = blockIdx.x;
  const int xcd = id & 7;
  const int j = id >> 3;          // 0..63
  const int half = j >> 5;        // 0: heavy, 1: light
  const int idx = j & 31;
  const int b = idx >> 3;
  const int nb = idx & 7;
  const int mb = half ? xcd : (15 - xcd);

  floatx4 acc[4][4] = {};
  gemm_core(P + (long)b * S * S, Ut + (long)b * D * S, S, 0, 2 * (mb + 1), mb,
            nb, acc);

  const int t = threadIdx.x;
  const int lane = t & 63, wave = t >> 6;
  const int rb = (wave >> 1) * 64 + (lane >> 4) * 4;
  const int cb = (wave & 1) * 64 + (lane & 15);
  const float* lrow = lsum + (long)b * S;

#pragma unroll
  for (int i = 0; i < 4; ++i) {
#pragma unroll
    for (int r = 0; r < 4; ++r) {
      const int row = mb * BM + rb + i * 16 + r;
      const float inv = 1.f / lrow[row];
#pragma unroll
      for (int j4 = 0; j4 < 4; ++j4) {
        const int col = nb * 128 + cb + j4 * 16;
        out[((long)b * S + row) * D + col] = acc[i][j4][r] * inv + bo[col];
      }
    }
  }
}

// ---------------- prep --------------------------------------------------
// [0,8192): cast x | [8192,11264): cast Wq,Wk,Wo | [11264,11520): Wv^T cast
// [11520,12544): bvo[d] = sum_v bv[v]*Wo[d][v] | 12544: zero lsum
__global__ void prep(const float* __restrict__ x, Ptr3 wp,
                     const float* __restrict__ Wv, const float* __restrict__ bv,
                     __bf16* __restrict__ xb, __bf16* __restrict__ Wb,
                     __bf16* __restrict__ Wvt, float* __restrict__ bvo,
                     float* __restrict__ lsum) {
  __shared__ __bf16 tile[64][66];
  __shared__ float wsum[4];
  const int bid = blockIdx.x;
  const int t = threadIdx.x;
  if (bid < 8192) {
    const long i = ((long)bid * 256 + t) * 4;
    const float4 f = *(const float4*)(x + i);
    bf16x4 o;
    o[0] = (__bf16)f.x; o[1] = (__bf16)f.y; o[2] = (__bf16)f.z; o[3] = (__bf16)f.w;
    *(bf16x4*)(xb + i) = o;
  } else if (bid < 11264) {
    const int slot = (bid - 8192) * 256 + t;
    const int which = slot >> 18;
    const long e = (long)(slot & 0x3ffff) * 4;
    const float4 f = *(const float4*)(wp.p[which] + e);
    bf16x4 o;
    o[0] = (__bf16)f.x; o[1] = (__bf16)f.y; o[2] = (__bf16)f.z; o[3] = (__bf16)f.w;
    *(bf16x4*)(Wb + ((long)which << 20) + e) = o;
  } else if (bid < 11520) {
    const int idx = bid - 11264;
    const int r0 = (idx >> 4) * 64, c0 = (idx & 15) * 64;
#pragma unroll
    for (int e = 0; e < 16; ++e) {
      const int i = e * 256 + t;
      const int r = i >> 6, c = i & 63;
      tile[r][c] = (__bf16)Wv[(long)(r0 + r) * 1024 + (c0 + c)];
    }
    __syncthreads();
#pragma unroll
    for (int e = 0; e < 16; ++e) {
      const int i = e * 256 + t;
      const int r = i >> 6, c = i & 63;
      Wvt[(long)(c0 + r) * 1024 + (r0 + c)] = tile[c][r];
    }
  } else if (bid < 12544) {
    const int d = bid - 11520;
    const float* row = wp.p[2] + (long)d * 1024;
    float s = 0.f;
    for (int v = t; v < 1024; v += 256) s += bv[v] * row[v];
#pragma unroll
    for (int off = 32; off > 0; off >>= 1) s += __shfl_down(s, off, 64);
    if ((t & 63) == 0) wsum[t >> 6] = s;
    __syncthreads();
    if (t == 0) bvo[d] = wsum[0] + wsum[1] + wsum[2] + wsum[3];
  } else {
#pragma unroll
    for (int e = 0; e < 8; ++e)
      *(float4*)(lsum + (e * 256 + t) * 4) = float4{0.f, 0.f, 0.f, 0.f};
  }
}

extern "C" void kernel_launch(void* const* d_in, const int* in_sizes, int n_in,
                              void* d_out, int out_size, void* d_ws, size_t ws_size,
                              hipStream_t stream) {
  const float* x = (const float*)d_in[0];
  const float* Wq = (const float*)d_in[1];
  const float* bq = (const float*)d_in[2];
  const float* Wk = (const float*)d_in[3];
  const float* bk = (const float*)d_in[4];
  const float* Wv = (const float*)d_in[5];
  const float* bv = (const float*)d_in[6];
  const float* Wo = (const float*)d_in[7];
  const float* bo = (const float*)d_in[8];
  float* out = (float*)d_out;

  constexpr int B = 4, S = 2048, D = 1024, KD = 1024;
  constexpr long MB_ = 1024 * 1024;

  char* w = (char*)d_ws;
  __bf16* xb = (__bf16*)(w);               // 16 MB
  __bf16* qk = (__bf16*)(w + 16 * MB_);    // 32 MB: q then k
  __bf16* Ut = (__bf16*)(w + 48 * MB_);    // 16 MB
  __bf16* P  = (__bf16*)(w + 64 * MB_);    // 32 MB
  __bf16* Wb = (__bf16*)(w + 96 * MB_);    // 6 MB: Wqb, Wkb, Wob
  __bf16* Wvt = (__bf16*)(w + 102 * MB_);  // 2 MB
  __bf16* Wvo = (__bf16*)(w + 104 * MB_);  // 2 MB
  float* lsum = (float*)(w + 106 * MB_);   // 32 KB
  float* bvo = (float*)(w + 106 * MB_ + 65536);  // 4 KB

  __bf16* Wob = Wb + (2l << 20);

  Ptr3 wp{{Wq, Wk, Wo}};
  prep<<<12545, 256, 0, stream>>>(x, wp, Wv, bv, xb, Wb, Wvt, bvo, lsum);

  fusedA<<<1088, 256, 0, stream>>>(xb, Wb, bq, bk, qk, Wob, Wvt, Wvo, S, KD, B);

  fusedB<<<1056, 256, 0, stream>>>(xb, Wvo, bvo, Ut, qk, qk + (long)B * S * KD,
                                   P, lsum, S, KD, D);

  gemm_pvo<<<512, 256, 0, stream>>>(P, Ut, lsum, bo, out, S, D);
}